// Round 1
// baseline (248.707 us; speedup 1.0000x reference)
//
#include <hip/hip_runtime.h>
#include <math.h>

#define B 128
#define N 2048
#define D 256
#define K 64
#define CH 16          // chunks per batch in main kernel
#define RPB (N / CH)   // rows per block = 128

// ---------------- workspace layout (in floats) ----------------
#define OFF_V       0                          // B*D = 32768
#define OFF_C2      (OFF_V + B * D)            // B
#define OFF_CNT     (OFF_C2 + B)               // B
#define OFF_SCORES  (OFF_CNT + B)              // B*N = 262144
#define OFF_PART    (OFF_SCORES + B * N)       // B*CH*D = 524288
#define OFF_SELIDX  (OFF_PART + B * CH * D)    // B*K ints = 8192
#define OFF_MODE    (OFF_SELIDX + B * K)       // 1 int

// ---------------- output layout (in floats) ----------------
#define O_TOK   0                      // B*K*D = 2097152
#define O_MASK  (O_TOK + B * K * D)    // B*K
#define O_IDX   (O_MASK + B * K)       // B*K
#define O_IMP   (O_IDX + B * K)        // B*K
#define O_GLOB  (O_IMP + B * K)        // B*D

__device__ __forceinline__ bool mask_at(const void* p, int mode, int i) {
    if (mode == 1) return ((const unsigned char*)p)[i] != 0;
    if (mode == 2) return ((const float*)p)[i] != 0.0f;
    return ((const int*)p)[i] != 0;
}

// Probe token_mask's storage dtype: bool-bytes (1B), int32, or float32.
__global__ void detect_mode_kernel(const unsigned int* __restrict__ w, int* __restrict__ mode_out) {
    int t = threadIdx.x; // 64 threads, scan 1024 words = 4KB (safe for any dtype)
    bool isF = false, hasHigh = false;
    for (int i = 0; i < 16; ++i) {
        unsigned int x = w[t * 16 + i];
        if (x == 0x3F800000u) isF = true;            // float 1.0
        if (x & 0xFFFFFF00u) hasHigh = true;         // bytes beyond LSB set
    }
    unsigned long long bf = __ballot(isF);
    unsigned long long bh = __ballot(hasHigh);
    if (t == 0) *mode_out = bf ? 2 : (bh ? 1 : 0);
}

// Per-batch: q = ego@Wq^T + bq; v = (q^T Wk)/16 + Ws; c2 = (q.bk)/16 + bs; cnt = sum(mask)
__global__ __launch_bounds__(256) void prep_kernel(
        const float* __restrict__ latent, const void* __restrict__ maskp,
        const int* __restrict__ modep,
        const float* __restrict__ Wq, const float* __restrict__ bq,
        const float* __restrict__ Wk, const float* __restrict__ bk,
        const float* __restrict__ Ws, const float* __restrict__ bs,
        float* __restrict__ v, float* __restrict__ c2, float* __restrict__ cnt) {
    int b = blockIdx.x, t = threadIdx.x;
    __shared__ float ego[D];
    __shared__ float q[D];
    ego[t] = latent[(size_t)b * N * D + t];
    __syncthreads();
    float acc = 0.f;
    const float* wq = Wq + (size_t)t * D;
    #pragma unroll 8
    for (int d = 0; d < D; ++d) acc = fmaf(ego[d], wq[d], acc);
    q[t] = acc + bq[t];
    __syncthreads();
    float a2 = 0.f;
    #pragma unroll 8
    for (int e = 0; e < D; ++e) a2 = fmaf(q[e], Wk[(size_t)e * D + t], a2);
    v[b * D + t] = a2 * 0.0625f + Ws[t];
    if (t < 64) {
        float p = 0.f;
        for (int j = 0; j < 4; ++j) { int e = t + 64 * j; p = fmaf(q[e], bk[e], p); }
        #pragma unroll
        for (int m = 32; m >= 1; m >>= 1) p += __shfl_xor(p, m, 64);
        if (t == 0) c2[b] = p * 0.0625f + bs[0];
    }
    int mode = *modep;
    int local = 0;
    for (int i = 0; i < N / D; ++i) local += mask_at(maskp, mode, b * N + t + D * i) ? 1 : 0;
    __shared__ int ctot;
    if (t == 0) ctot = 0;
    __syncthreads();
    atomicAdd(&ctot, local);
    __syncthreads();
    if (t == 0) cnt[b] = (float)ctot;
}

// Streaming pass: scores (masked) + partial column sums for global_latent.
__global__ __launch_bounds__(256) void main_kernel(
        const float* __restrict__ latent, const void* __restrict__ maskp,
        const int* __restrict__ modep,
        const float* __restrict__ v, const float* __restrict__ c2,
        float* __restrict__ scores, float* __restrict__ partials) {
    int b = blockIdx.y, ch = blockIdx.x;
    int t = threadIdx.x, w = t >> 6, l = t & 63;
    int mode = *modep;
    float4 vv = ((const float4*)(v + b * D))[l];
    float c2b = c2[b];
    float ax = 0.f, ay = 0.f, az = 0.f, aw = 0.f;
    int n0 = ch * RPB + w * (RPB / 4);
    const float4* lat4 = (const float4*)(latent + (size_t)b * N * D);
    for (int i = 0; i < RPB / 4; ++i) {
        int n = n0 + i;
        float4 x = lat4[(size_t)n * (D / 4) + l];
        float p = x.x * vv.x;
        p = fmaf(x.y, vv.y, p);
        p = fmaf(x.z, vv.z, p);
        p = fmaf(x.w, vv.w, p);
        #pragma unroll
        for (int m = 32; m >= 1; m >>= 1) p += __shfl_xor(p, m, 64);
        bool msk = mask_at(maskp, mode, b * N + n);
        if (l == 0) scores[(size_t)b * N + n] = msk ? (p + c2b) : -INFINITY;
        if (msk) { ax += x.x; ay += x.y; az += x.z; aw += x.w; }
    }
    __shared__ float red[4][D];
    red[w][l * 4 + 0] = ax; red[w][l * 4 + 1] = ay;
    red[w][l * 4 + 2] = az; red[w][l * 4 + 3] = aw;
    __syncthreads();
    float s = red[0][t] + red[1][t] + red[2][t] + red[3][t];
    partials[((size_t)b * CH + ch) * D + t] = s;
}

// One wave per batch: iterative argmax top-K (jax tie semantics), then importance softmax.
__global__ __launch_bounds__(256) void topk_kernel(
        const float* __restrict__ scores, const void* __restrict__ maskp,
        const int* __restrict__ modep,
        float* __restrict__ out_mask, float* __restrict__ out_idx,
        float* __restrict__ out_imp, int* __restrict__ selidx) {
    int t = threadIdx.x, w = t >> 6, l = t & 63;
    int b = blockIdx.x * 4 + w;
    __shared__ float sc[4][N];
    for (int i = 0; i < N / 64; ++i) sc[w][i * 64 + l] = scores[(size_t)b * N + i * 64 + l];
    asm volatile("s_waitcnt lgkmcnt(0)" ::: "memory");
    float selv = 0.f; int seli = 0;
    const float NANF = __uint_as_float(0x7FC00000u);
    for (int it = 0; it < K; ++it) {
        float bv = -INFINITY; int bi = 0x7FFFFFFF;
        #pragma unroll
        for (int i = 0; i < N / 64; ++i) {
            int pos = l + 64 * i;
            float x = sc[w][pos];
            if (x > bv || (x == bv && pos < bi)) { bv = x; bi = pos; }
        }
        #pragma unroll
        for (int m = 1; m <= 32; m <<= 1) {
            float ov = __shfl_xor(bv, m, 64);
            int oi = __shfl_xor(bi, m, 64);
            if (ov > bv || (ov == bv && oi < bi)) { bv = ov; bi = oi; }
        }
        if (l == it) { selv = bv; seli = bi; }
        if (l == (bi & 63)) sc[w][bi] = NANF;  // NaN: never re-selected, -inf ties stay distinct
        asm volatile("s_waitcnt lgkmcnt(0)" ::: "memory");
    }
    int mode = *modep;
    bool m = mask_at(maskp, mode, b * N + seli);
    float x = m ? selv : -1e9f;
    float mx = x;
    #pragma unroll
    for (int mm = 1; mm <= 32; mm <<= 1) mx = fmaxf(mx, __shfl_xor(mx, mm, 64));
    float e = expf(x - mx);
    float sm = e;
    #pragma unroll
    for (int mm = 1; mm <= 32; mm <<= 1) sm += __shfl_xor(sm, mm, 64);
    out_idx[b * K + l] = (float)seli;
    out_mask[b * K + l] = m ? 1.f : 0.f;
    out_imp[b * K + l] = e / sm;
    selidx[b * K + l] = seli;
}

__global__ __launch_bounds__(256) void gather_kernel(
        const float* __restrict__ latent, const int* __restrict__ selidx,
        float* __restrict__ out_tok) {
    int t = threadIdx.x;
    int r = blockIdx.x * 4 + (t >> 6);
    int l = t & 63;
    int b = r >> 6;
    int idx = selidx[r];
    float4 x = ((const float4*)(latent + ((size_t)b * N + idx) * D))[l];
    ((float4*)(out_tok + (size_t)r * D))[l] = x;
}

__global__ __launch_bounds__(256) void finalize_kernel(
        const float* __restrict__ partials, const float* __restrict__ cnt,
        float* __restrict__ out_g) {
    int b = blockIdx.x, t = threadIdx.x;
    float s = 0.f;
    for (int ch = 0; ch < CH; ++ch) s += partials[((size_t)b * CH + ch) * D + t];
    out_g[b * D + t] = s / cnt[b];
}

extern "C" void kernel_launch(void* const* d_in, const int* in_sizes, int n_in,
                              void* d_out, int out_size, void* d_ws, size_t ws_size,
                              hipStream_t stream) {
    const float* latent = (const float*)d_in[0];
    const void*  maskp  = d_in[1];
    const float* Wq = (const float*)d_in[2];
    const float* bq = (const float*)d_in[3];
    const float* Wk = (const float*)d_in[4];
    const float* bk = (const float*)d_in[5];
    const float* Ws = (const float*)d_in[6];
    const float* bs = (const float*)d_in[7];

    float* ws = (float*)d_ws;
    float* v      = ws + OFF_V;
    float* c2     = ws + OFF_C2;
    float* cnt    = ws + OFF_CNT;
    float* scores = ws + OFF_SCORES;
    float* part   = ws + OFF_PART;
    int*   selidx = (int*)(ws + OFF_SELIDX);
    int*   modep  = (int*)(ws + OFF_MODE);
    float* out = (float*)d_out;

    hipLaunchKernelGGL(detect_mode_kernel, dim3(1), dim3(64), 0, stream,
                       (const unsigned int*)maskp, modep);
    hipLaunchKernelGGL(prep_kernel, dim3(B), dim3(256), 0, stream,
                       latent, maskp, modep, Wq, bq, Wk, bk, Ws, bs, v, c2, cnt);
    hipLaunchKernelGGL(main_kernel, dim3(CH, B), dim3(256), 0, stream,
                       latent, maskp, modep, v, c2, scores, part);
    hipLaunchKernelGGL(topk_kernel, dim3(B / 4), dim3(256), 0, stream,
                       scores, maskp, modep, out + O_MASK, out + O_IDX, out + O_IMP, selidx);
    hipLaunchKernelGGL(gather_kernel, dim3(B * K / 4), dim3(256), 0, stream,
                       latent, selidx, out + O_TOK);
    hipLaunchKernelGGL(finalize_kernel, dim3(B), dim3(256), 0, stream,
                       part, cnt, out + O_GLOB);
}

// Round 2
// 136.952 us; speedup vs baseline: 1.8160x; 1.8160x over previous
//
#include <hip/hip_runtime.h>
#include <math.h>

#define B 128
#define N 2048
#define D 256
#define K 64
#define CH 16          // chunks per batch in main kernel
#define RPB (N / CH)   // rows per block = 128

// ---------------- workspace layout (in floats) ----------------
#define OFF_V       0                          // B*D = 32768
#define OFF_C2      (OFF_V + B * D)            // B
#define OFF_CNT     (OFF_C2 + B)               // B
#define OFF_SCORES  (OFF_CNT + B)              // B*N = 262144
#define OFF_PART    (OFF_SCORES + B * N)       // B*CH*D = 524288
#define OFF_SELIDX  (OFF_PART + B * CH * D)    // B*K ints = 8192
#define OFF_MODE    (OFF_SELIDX + B * K)       // 1 int

// ---------------- output layout (in floats) ----------------
#define O_TOK   0                      // B*K*D = 2097152
#define O_MASK  (O_TOK + B * K * D)    // B*K
#define O_IDX   (O_MASK + B * K)      // B*K
#define O_IMP   (O_IDX + B * K)       // B*K
#define O_GLOB  (O_IMP + B * K)       // B*D

__device__ __forceinline__ bool mask_at(const void* p, int mode, int i) {
    if (mode == 1) return ((const unsigned char*)p)[i] != 0;
    if (mode == 2) return ((const float*)p)[i] != 0.0f;
    return ((const int*)p)[i] != 0;
}

// Probe token_mask's storage dtype: bool-bytes (1B), int32, or float32.
__global__ void detect_mode_kernel(const unsigned int* __restrict__ w, int* __restrict__ mode_out) {
    int t = threadIdx.x; // 64 threads, scan 1024 words = 4KB (safe for any dtype)
    bool isF = false, hasHigh = false;
    for (int i = 0; i < 16; ++i) {
        unsigned int x = w[t * 16 + i];
        if (x == 0x3F800000u) isF = true;            // float 1.0
        if (x & 0xFFFFFF00u) hasHigh = true;         // bytes beyond LSB set
    }
    unsigned long long bf = __ballot(isF);
    unsigned long long bh = __ballot(hasHigh);
    if (t == 0) *mode_out = bf ? 2 : (bh ? 1 : 0);
}

// Per-batch: q = ego@Wq^T + bq; v = (q^T Wk)/16 + Ws; c2 = (q.bk)/16 + bs; cnt = sum(mask)
__global__ __launch_bounds__(256) void prep_kernel(
        const float* __restrict__ latent, const void* __restrict__ maskp,
        const int* __restrict__ modep,
        const float* __restrict__ Wq, const float* __restrict__ bq,
        const float* __restrict__ Wk, const float* __restrict__ bk,
        const float* __restrict__ Ws, const float* __restrict__ bs,
        float* __restrict__ v, float* __restrict__ c2, float* __restrict__ cnt) {
    int b = blockIdx.x, t = threadIdx.x;
    __shared__ float ego[D];
    __shared__ float q[D];
    ego[t] = latent[(size_t)b * N * D + t];
    __syncthreads();
    float acc = 0.f;
    const float* wq = Wq + (size_t)t * D;
    #pragma unroll 8
    for (int d = 0; d < D; ++d) acc = fmaf(ego[d], wq[d], acc);
    q[t] = acc + bq[t];
    __syncthreads();
    float a2 = 0.f;
    #pragma unroll 8
    for (int e = 0; e < D; ++e) a2 = fmaf(q[e], Wk[(size_t)e * D + t], a2);
    v[b * D + t] = a2 * 0.0625f + Ws[t];
    if (t < 64) {
        float p = 0.f;
        for (int j = 0; j < 4; ++j) { int e = t + 64 * j; p = fmaf(q[e], bk[e], p); }
        #pragma unroll
        for (int m = 32; m >= 1; m >>= 1) p += __shfl_xor(p, m, 64);
        if (t == 0) c2[b] = p * 0.0625f + bs[0];
    }
    int mode = *modep;
    int local = 0;
    for (int i = 0; i < N / D; ++i) local += mask_at(maskp, mode, b * N + t + D * i) ? 1 : 0;
    __shared__ int ctot;
    if (t == 0) ctot = 0;
    __syncthreads();
    atomicAdd(&ctot, local);
    __syncthreads();
    if (t == 0) cnt[b] = (float)ctot;
}

// Streaming pass: scores (masked) + partial column sums for global_latent.
__global__ __launch_bounds__(256) void main_kernel(
        const float* __restrict__ latent, const void* __restrict__ maskp,
        const int* __restrict__ modep,
        const float* __restrict__ v, const float* __restrict__ c2,
        float* __restrict__ scores, float* __restrict__ partials) {
    int b = blockIdx.y, ch = blockIdx.x;
    int t = threadIdx.x, w = t >> 6, l = t & 63;
    int mode = *modep;
    float4 vv = ((const float4*)(v + b * D))[l];
    float c2b = c2[b];
    float ax = 0.f, ay = 0.f, az = 0.f, aw = 0.f;
    int n0 = ch * RPB + w * (RPB / 4);
    const float4* lat4 = (const float4*)(latent + (size_t)b * N * D);
    for (int i = 0; i < RPB / 4; ++i) {
        int n = n0 + i;
        float4 x = lat4[(size_t)n * (D / 4) + l];
        float p = x.x * vv.x;
        p = fmaf(x.y, vv.y, p);
        p = fmaf(x.z, vv.z, p);
        p = fmaf(x.w, vv.w, p);
        #pragma unroll
        for (int m = 32; m >= 1; m >>= 1) p += __shfl_xor(p, m, 64);
        bool msk = mask_at(maskp, mode, b * N + n);
        if (l == 0) scores[(size_t)b * N + n] = msk ? (p + c2b) : -INFINITY;
        if (msk) { ax += x.x; ay += x.y; az += x.z; aw += x.w; }
    }
    __shared__ float red[4][D];
    red[w][l * 4 + 0] = ax; red[w][l * 4 + 1] = ay;
    red[w][l * 4 + 2] = az; red[w][l * 4 + 3] = aw;
    __syncthreads();
    float s = red[0][t] + red[1][t] + red[2][t] + red[3][t];
    partials[((size_t)b * CH + ch) * D + t] = s;
}

// Radix-select top-K per batch (one block per batch), then bitonic sort K pairs
// on wave 0 (value desc, index asc = jax.lax.top_k stable semantics), then
// fused mask/softmax epilogue.
__global__ __launch_bounds__(256) void topk_kernel(
        const float* __restrict__ scores, const void* __restrict__ maskp,
        const int* __restrict__ modep,
        float* __restrict__ out_mask, float* __restrict__ out_idx,
        float* __restrict__ out_imp, int* __restrict__ selidx) {
    int b = blockIdx.x, t = threadIdx.x;
    __shared__ unsigned int keys[N];
    __shared__ unsigned int hist[256];
    __shared__ int pgA[256], peA[256];
    __shared__ unsigned int selu[K];
    __shared__ int seliA[K];
    __shared__ unsigned int s_byte;
    __shared__ int s_kneed;

    // load + order-preserving float->uint map
    for (int i = 0; i < N / 256; ++i) {
        int pos = t + 256 * i;
        unsigned int fu = __float_as_uint(scores[(size_t)b * N + pos]);
        keys[pos] = (fu & 0x80000000u) ? ~fu : (fu | 0x80000000u);
    }
    __syncthreads();

    // 4-pass radix select: find K-th largest key T and tie budget kneed
    unsigned int prefixKey = 0;
    int kneed = K;
    for (int shift = 24; shift >= 0; shift -= 8) {
        hist[t] = 0;
        __syncthreads();
        for (int i = 0; i < N / 256; ++i) {
            unsigned int u = keys[t * (N / 256) + i];
            bool match = (shift == 24) || ((u >> (shift + 8)) == (prefixKey >> (shift + 8)));
            if (match) atomicAdd(&hist[(u >> shift) & 0xFFu], 1u);
        }
        __syncthreads();
        if (t == 0) {
            int acc = 0, bsel = 0;
            for (int bb = 255; bb >= 0; --bb) {
                int h = (int)hist[bb];
                if (acc + h >= kneed) { bsel = bb; break; }
                acc += h;
            }
            s_byte = (unsigned int)bsel;
            s_kneed = kneed - acc;
        }
        __syncthreads();
        prefixKey |= (s_byte << shift);
        kneed = s_kneed;
        __syncthreads();
    }
    unsigned int T = prefixKey;

    // per-thread counts over contiguous chunk (index order preserved)
    int cGT = 0, cEQ = 0;
    for (int i = 0; i < N / 256; ++i) {
        unsigned int u = keys[t * (N / 256) + i];
        cGT += (u > T);
        cEQ += (u == T);
    }
    pgA[t] = cGT; peA[t] = cEQ;
    __syncthreads();
    // Hillis-Steele inclusive scan over 256 threads
    for (int off = 1; off < 256; off <<= 1) {
        int a = (t >= off) ? pgA[t - off] : 0;
        int e = (t >= off) ? peA[t - off] : 0;
        __syncthreads();
        pgA[t] += a; peA[t] += e;
        __syncthreads();
    }
    int totGT = pgA[255];            // count of keys strictly > T (< K)
    int pg = pgA[t] - cGT;           // exclusive prefixes
    int pe = peA[t] - cEQ;
    // collect: all > T, plus the kneed lowest-indexed == T
    for (int i = 0; i < N / 256; ++i) {
        int pos = t * (N / 256) + i;
        unsigned int u = keys[pos];
        if (u > T) {
            selu[pg] = u; seliA[pg] = pos; ++pg;
        } else if (u == T) {
            if (pe < kneed) { selu[totGT + pe] = u; seliA[totGT + pe] = pos; }
            ++pe;
        }
    }
    __syncthreads();

    if (t < K) {
        int l = t;
        unsigned int u = selu[l];
        int pos = seliA[l];
        // bitonic sort 64 pairs across wave 0, descending by (u, then -pos)
        #pragma unroll
        for (int k2 = 2; k2 <= 64; k2 <<= 1) {
            #pragma unroll
            for (int j = k2 >> 1; j >= 1; j >>= 1) {
                unsigned int ou = __shfl_xor(u, j, 64);
                int opos = __shfl_xor(pos, j, 64);
                bool lower = (l & j) == 0;
                bool descB = (l & k2) == 0;
                bool otherGreater = (ou > u) || (ou == u && opos < pos);
                if (otherGreater == (lower == descB)) { u = ou; pos = opos; }
            }
        }
        // unmap key -> float score
        unsigned int fu = (u & 0x80000000u) ? (u ^ 0x80000000u) : ~u;
        float selv = __uint_as_float(fu);

        int mode = *modep;
        bool m = mask_at(maskp, mode, b * N + pos);
        float x = m ? selv : -1e9f;
        float mx = x;
        #pragma unroll
        for (int mm = 1; mm <= 32; mm <<= 1) mx = fmaxf(mx, __shfl_xor(mx, mm, 64));
        float e = expf(x - mx);
        float sm = e;
        #pragma unroll
        for (int mm = 1; mm <= 32; mm <<= 1) sm += __shfl_xor(sm, mm, 64);
        out_idx[b * K + l] = (float)pos;
        out_mask[b * K + l] = m ? 1.f : 0.f;
        out_imp[b * K + l] = e / sm;
        selidx[b * K + l] = pos;
    }
}

__global__ __launch_bounds__(256) void gather_kernel(
        const float* __restrict__ latent, const int* __restrict__ selidx,
        float* __restrict__ out_tok) {
    int t = threadIdx.x;
    int r = blockIdx.x * 4 + (t >> 6);
    int l = t & 63;
    int b = r >> 6;
    int idx = selidx[r];
    float4 x = ((const float4*)(latent + ((size_t)b * N + idx) * D))[l];
    ((float4*)(out_tok + (size_t)r * D))[l] = x;
}

__global__ __launch_bounds__(256) void finalize_kernel(
        const float* __restrict__ partials, const float* __restrict__ cnt,
        float* __restrict__ out_g) {
    int b = blockIdx.x, t = threadIdx.x;
    float s = 0.f;
    for (int ch = 0; ch < CH; ++ch) s += partials[((size_t)b * CH + ch) * D + t];
    out_g[b * D + t] = s / cnt[b];
}

extern "C" void kernel_launch(void* const* d_in, const int* in_sizes, int n_in,
                              void* d_out, int out_size, void* d_ws, size_t ws_size,
                              hipStream_t stream) {
    const float* latent = (const float*)d_in[0];
    const void*  maskp  = d_in[1];
    const float* Wq = (const float*)d_in[2];
    const float* bq = (const float*)d_in[3];
    const float* Wk = (const float*)d_in[4];
    const float* bk = (const float*)d_in[5];
    const float* Ws = (const float*)d_in[6];
    const float* bs = (const float*)d_in[7];

    float* ws = (float*)d_ws;
    float* v      = ws + OFF_V;
    float* c2     = ws + OFF_C2;
    float* cnt    = ws + OFF_CNT;
    float* scores = ws + OFF_SCORES;
    float* part   = ws + OFF_PART;
    int*   selidx = (int*)(ws + OFF_SELIDX);
    int*   modep  = (int*)(ws + OFF_MODE);
    float* out = (float*)d_out;

    hipLaunchKernelGGL(detect_mode_kernel, dim3(1), dim3(64), 0, stream,
                       (const unsigned int*)maskp, modep);
    hipLaunchKernelGGL(prep_kernel, dim3(B), dim3(256), 0, stream,
                       latent, maskp, modep, Wq, bq, Wk, bk, Ws, bs, v, c2, cnt);
    hipLaunchKernelGGL(main_kernel, dim3(CH, B), dim3(256), 0, stream,
                       latent, maskp, modep, v, c2, scores, part);
    hipLaunchKernelGGL(topk_kernel, dim3(B), dim3(256), 0, stream,
                       scores, maskp, modep, out + O_MASK, out + O_IDX, out + O_IMP, selidx);
    hipLaunchKernelGGL(gather_kernel, dim3(B * K / 4), dim3(256), 0, stream,
                       latent, selidx, out + O_TOK);
    hipLaunchKernelGGL(finalize_kernel, dim3(B), dim3(256), 0, stream,
                       part, cnt, out + O_GLOB);
}